// Round 3
// baseline (312.382 us; speedup 1.0000x reference)
//
#include <hip/hip_runtime.h>
#include <hip/hip_bf16.h>
#include <stdint.h>

// Problem constants (from reference)
static constexpr int V_N = 50000;
static constexpr int E_N = 10000;
static constexpr int Q_N = 32;
static constexpr int F_N = 256;        // F_DIM == OUT_DIM == 256
static constexpr int SLOT_STRIDE = 40; // max degree slots (Poisson mean 6.4)
static constexpr int NWV = (F_N * F_N) / 4;      // 16,384 vec4s of W
static constexpr int T_TILES = E_N / 8;          // 1250 edge-tiles (8 edges)
static constexpr int LDS_STRIDE = 264;           // 256 + 8 pad
static constexpr int VFLT = V_N * F_N;           // floats per batch of X

// prep: 512 blocks; 16 convert W, 496 build buckets
static constexpr int PREP_GRID = 512;
static constexpr int WBLK = 16;
static constexpr int BBLK = PREP_GRID - WBLK;

typedef unsigned short us;
typedef float f32x4 __attribute__((ext_vector_type(4)));
typedef us us4 __attribute__((ext_vector_type(4)));
typedef us us8 __attribute__((ext_vector_type(8)));
typedef __bf16 bf16x8 __attribute__((ext_vector_type(8)));

__device__ __forceinline__ us f2b(float f) {
  unsigned x = __builtin_bit_cast(unsigned, f);
  x += 0x7fffu + ((x >> 16) & 1u);   // round-to-nearest-even
  return (us)(x >> 16);
}
__device__ __forceinline__ float b2f(us u) {
  unsigned x = ((unsigned)u) << 16;
  return __builtin_bit_cast(float, x);
}

// ---- P0: W fp32->bf16 + bucket build (tiny; X is NOT staged anymore) -------

__global__ __launch_bounds__(256) void k_prep(
    const float* __restrict__ Wm, const int* __restrict__ en,
    us* __restrict__ Wb, int* __restrict__ cnt, int* __restrict__ slots) {
  const int bx = blockIdx.x;
  if (bx < WBLK) {
    const int tid = bx * 256 + (int)threadIdx.x;
    for (int i = tid; i < NWV; i += WBLK * 256) {
      f32x4 v = ((const f32x4*)Wm)[i];
      us4 o;
      #pragma unroll
      for (int j = 0; j < 4; ++j) o[j] = f2b(v[j]);
      ((us4*)Wb)[i] = o;
    }
  } else {
    const int tid = (bx - WBLK) * 256 + (int)threadIdx.x;
    for (int i = tid; i < E_N * Q_N; i += BBLK * 256) {
      int v = en[i];
      int pos = atomicAdd(&cnt[v], 1);
      if (pos < SLOT_STRIDE) slots[v * SLOT_STRIDE + pos] = i >> 5;  // edge id
    }
  }
}

// ---- P1: fused edge-mean (fp32 gather, L3-resident X) + bf16 GEMM ----------
// One 8-edge tile per block; wave w aggregates edges e0=8t+2w, e0+1.
// Per q: 4 coalesced 1KB wave loads (f32x4/lane) — edge{0,1} x batch{0,1}.
// LDS tile rows 0-7: batch0 edges, rows 8-15: batch1. Row-major, stride 264.

__global__ __launch_bounds__(256) void k_agg_gemm(
    const float* __restrict__ X, const int* __restrict__ en,
    const us* __restrict__ Wb, us* __restrict__ Yb) {
  __shared__ us tile[16 * LDS_STRIDE];
  const int t = blockIdx.x;
  const int w = threadIdx.x >> 6;
  const int lane = threadIdx.x & 63;
  const int m = lane & 15;
  const int quad = lane >> 4;
  const int col4 = lane * 4;           // f32x4 column (4 floats/lane)

  const int e0 = t * 8 + 2 * w;
  int n0 = en[e0 * Q_N + (lane & 31)];
  int n1 = en[(e0 + 1) * Q_N + (lane & 31)];
  const float* X0 = X + col4;          // batch 0
  const float* X1 = X + (size_t)VFLT + col4;  // batch 1
  float a00[4] = {0, 0, 0, 0}, a01[4] = {0, 0, 0, 0};
  float a10[4] = {0, 0, 0, 0}, a11[4] = {0, 0, 0, 0};
  #pragma unroll 4
  for (int q = 0; q < Q_N; ++q) {      // 16 independent 16B loads in flight
    int ma = __shfl(n0, q, 64);
    int mb = __shfl(n1, q, 64);
    f32x4 v0a = *(const f32x4*)(X0 + (size_t)ma * F_N);
    f32x4 v1a = *(const f32x4*)(X1 + (size_t)ma * F_N);
    f32x4 v0b = *(const f32x4*)(X0 + (size_t)mb * F_N);
    f32x4 v1b = *(const f32x4*)(X1 + (size_t)mb * F_N);
    #pragma unroll
    for (int j = 0; j < 4; ++j) {
      a00[j] += v0a[j]; a01[j] += v1a[j];
      a10[j] += v0b[j]; a11[j] += v1b[j];
    }
  }
  const float sc = 1.0f / 32.0f;
  us4 o00, o01, o10, o11;
  #pragma unroll
  for (int j = 0; j < 4; ++j) {
    o00[j] = f2b(a00[j] * sc); o01[j] = f2b(a01[j] * sc);
    o10[j] = f2b(a10[j] * sc); o11[j] = f2b(a11[j] * sc);
  }
  *(us4*)(tile + (2 * w) * LDS_STRIDE + col4) = o00;          // b0, edge e0
  *(us4*)(tile + (2 * w + 1) * LDS_STRIDE + col4) = o10;      // b0, edge e0+1
  *(us4*)(tile + (8 + 2 * w) * LDS_STRIDE + col4) = o01;      // b1, edge e0
  *(us4*)(tile + (8 + 2 * w + 1) * LDS_STRIDE + col4) = o11;  // b1, edge e0+1
  __syncthreads();

  // A-fragments from LDS (reused across this wave's 4 n-tiles)
  bf16x8 af[8];
  #pragma unroll
  for (int kk = 0; kk < 8; ++kk)
    af[kk] = *(const bf16x8*)(tile + m * LDS_STRIDE + quad * 8 + kk * 32);
  #pragma unroll
  for (int i = 0; i < 4; ++i) {
    const int nt = w * 4 + i;
    const us* bp = Wb + (size_t)(nt * 16 + m) * F_N + quad * 8;
    f32x4 acc = {0.f, 0.f, 0.f, 0.f};
    #pragma unroll
    for (int kk = 0; kk < 8; ++kk) {
      bf16x8 bv = *(const bf16x8*)(bp + kk * 32);
      acc = __builtin_amdgcn_mfma_f32_16x16x32_bf16(af[kk], bv, acc, 0, 0, 0);
    }
    #pragma unroll
    for (int r2 = 0; r2 < 4; ++r2) {
      int dr = quad * 4 + r2;            // D row within 16-row tile
      int e = t * 8 + (dr & 7);
      int b = dr >> 3;
      Yb[((size_t)e * 2 + b) * 256 + nt * 16 + m] = f2b(acc[r2]);  // [e][b][f]
    }
  }
}

// ---- P2: out[b,v,:] = bias + (1/deg) * sum_{e in slots(v)} Y[e,b,:] --------
// Yb [e][b][f]: each per-slot read is ONE coalesced 1KB wave load.

__global__ __launch_bounds__(256) void k_out(
    const us* __restrict__ Yb, const int* __restrict__ cnt,
    const int* __restrict__ slots, const float* __restrict__ bias,
    float* __restrict__ out) {
  const int w = threadIdx.x >> 6;
  const int lane = threadIdx.x & 63;
  const int v = blockIdx.x * 4 + w;
  const int half = lane >> 5;          // batch
  const int col8 = (lane & 31) * 8;
  int c = cnt[v];
  if (c > SLOT_STRIDE) c = SLOT_STRIDE;
  const int* sb = slots + (size_t)v * SLOT_STRIDE;
  const us* Yg = Yb + half * 256 + col8;
  float acc[8] = {0, 0, 0, 0, 0, 0, 0, 0};
  int j = 0;
  for (; j + 4 <= c; j += 4) {
    int ea = sb[j], eb = sb[j + 1], ec = sb[j + 2], ed = sb[j + 3];
    us8 pa = *(const us8*)(Yg + (size_t)ea * 512);
    us8 pb = *(const us8*)(Yg + (size_t)eb * 512);
    us8 pc = *(const us8*)(Yg + (size_t)ec * 512);
    us8 pd = *(const us8*)(Yg + (size_t)ed * 512);
    #pragma unroll
    for (int k = 0; k < 8; ++k)
      acc[k] += (b2f(pa[k]) + b2f(pb[k])) + (b2f(pc[k]) + b2f(pd[k]));
  }
  for (; j < c; ++j) {
    int e = sb[j];
    us8 p = *(const us8*)(Yg + (size_t)e * 512);
    #pragma unroll
    for (int k = 0; k < 8; ++k) acc[k] += b2f(p[k]);
  }
  float inv = 1.0f / (float)(c > 0 ? c : 1);
  f32x4 b0 = *(const f32x4*)(bias + col8);
  f32x4 b1 = *(const f32x4*)(bias + col8 + 4);
  f32x4 r0, r1;
  #pragma unroll
  for (int k = 0; k < 4; ++k) {
    r0[k] = b0[k] + acc[k] * inv;
    r1[k] = b1[k] + acc[4 + k] * inv;
  }
  float* op = out + ((size_t)half * V_N + v) * 256 + col8;
  __builtin_nontemporal_store(r0, (f32x4*)op);       // streaming, never re-read
  __builtin_nontemporal_store(r1, (f32x4*)(op + 4));
}

// ---- launch -----------------------------------------------------------------

extern "C" void kernel_launch(void* const* d_in, const int* in_sizes, int n_in,
                              void* d_out, int out_size, void* d_ws, size_t ws_size,
                              hipStream_t stream) {
  (void)in_sizes; (void)n_in; (void)out_size; (void)ws_size;
  const float* X = (const float*)d_in[0];    // (B,V,F) fp32
  const int* en = (const int*)d_in[1];       // (E,Q) int32
  const float* Wm = (const float*)d_in[2];   // (OUT,F) fp32
  const float* bias = (const float*)d_in[3]; // (OUT,) fp32
  float* out = (float*)d_out;                // (B,V,OUT) fp32

  char* ws = (char*)d_ws;
  int* cnt   = (int*)(ws);                    // V ints = 200,000 B
  int* slots = (int*)(ws + (1u << 20));       // V*40 ints = 8,000,000 B
  us*  Wb    = (us*)(ws + (10u << 20));       // 256*256 bf16 = 131,072 B
  us*  Yb    = (us*)(ws + (11u << 20));       // 2E*256 bf16 = 10,240,000 B

  hipMemsetAsync(cnt, 0, V_N * sizeof(int), stream);
  k_prep<<<PREP_GRID, 256, 0, stream>>>(Wm, en, Wb, cnt, slots);
  k_agg_gemm<<<T_TILES, 256, 0, stream>>>(X, en, Wb, Yb);
  k_out<<<V_N / 4, 256, 0, stream>>>(Yb, cnt, slots, bias, out);
}

// Round 5
// 291.619 us; speedup vs baseline: 1.0712x; 1.0712x over previous
//
#include <hip/hip_runtime.h>
#include <hip/hip_bf16.h>
#include <stdint.h>

// Problem constants (from reference)
static constexpr int V_N = 50000;
static constexpr int E_N = 10000;
static constexpr int Q_N = 32;
static constexpr int F_N = 256;        // F_DIM == OUT_DIM == 256
static constexpr int SLOT_STRIDE = 40; // max degree slots (Poisson mean 6.4)
static constexpr int VF4 = V_N * F_N / 4;        // 3,200,000 vec4 per batch
static constexpr int NXV = 2 * VF4;              // 6,400,000 vec4s of X
static constexpr int NWV = (F_N * F_N) / 4;      // 16,384 vec4s of W
static constexpr int T_TILES = E_N / 8;          // 1250 edge-tiles (8 edges)
static constexpr int LDS_STRIDE = 264;           // 256 + 8 pad

// prep role split: blockIdx%4 in {0,1,2} -> X convert, %4==3 -> W/bucket
static constexpr int PREP_GRID = 2048;
static constexpr int XNT = 1536 * 256;           // X-convert threads (mult of 64)
static constexpr int WBLK = 16;
static constexpr int BBLK = 512 - WBLK;          // 496 bucket blocks

typedef unsigned short us;
typedef float f32x4 __attribute__((ext_vector_type(4)));
typedef us us4 __attribute__((ext_vector_type(4)));
typedef us us8 __attribute__((ext_vector_type(8)));
typedef __bf16 bf16x8 __attribute__((ext_vector_type(8)));

__device__ __forceinline__ us f2b(float f) {
  unsigned x = __builtin_bit_cast(unsigned, f);
  x += 0x7fffu + ((x >> 16) & 1u);   // round-to-nearest-even
  return (us)(x >> 16);
}
__device__ __forceinline__ float b2f(us u) {
  unsigned x = ((unsigned)u) << 16;
  return __builtin_bit_cast(float, x);
}

// vec4 index i over fp32 X[b][v][f]  ->  vec4 index into Xb[v][b][f]
// (wave bases are multiples of 64 and VF4 % 64 == 0, so per-wave stores stay
//  contiguous 512B chunks and no wave straddles the batch boundary)
__device__ __forceinline__ int xidx(int i) {
  int b = (i >= VF4) ? 1 : 0;
  int r2 = i - b * VF4;
  return ((r2 >> 6) << 7) + (b << 6) + (r2 & 63);
}

// ---- P0: fp32->bf16 staging of X,W + bucket-build (role-specialized) -------
// X is read with NON-TEMPORAL loads: it is touched exactly once, and keeping
// it out of L3 leaves the cache for Xb (re-read 6.4x by the gather).

__global__ __launch_bounds__(256) void k_prep_bucket(
    const float* __restrict__ X, const float* __restrict__ Wm,
    const int* __restrict__ en, us* __restrict__ Xb, us* __restrict__ Wb,
    int* __restrict__ cnt, int* __restrict__ slots) {
  const int bx = blockIdx.x;
  const int r = bx & 3;
  if (r != 3) {
    // ---- X conversion: 1536 blocks, 4-way unrolled (64B reads/lane in flight)
    const int tid = ((bx >> 2) * 3 + r) * 256 + (int)threadIdx.x;
    int i = tid;
    for (; i + 3 * XNT < NXV; i += 4 * XNT) {
      f32x4 va = __builtin_nontemporal_load(&((const f32x4*)X)[i]);
      f32x4 vb = __builtin_nontemporal_load(&((const f32x4*)X)[i + XNT]);
      f32x4 vc = __builtin_nontemporal_load(&((const f32x4*)X)[i + 2 * XNT]);
      f32x4 vd = __builtin_nontemporal_load(&((const f32x4*)X)[i + 3 * XNT]);
      us4 oa, ob, oc, od;
      #pragma unroll
      for (int j = 0; j < 4; ++j) {
        oa[j] = f2b(va[j]); ob[j] = f2b(vb[j]);
        oc[j] = f2b(vc[j]); od[j] = f2b(vd[j]);
      }
      ((us4*)Xb)[xidx(i)] = oa;
      ((us4*)Xb)[xidx(i + XNT)] = ob;
      ((us4*)Xb)[xidx(i + 2 * XNT)] = oc;
      ((us4*)Xb)[xidx(i + 3 * XNT)] = od;
    }
    for (; i < NXV; i += XNT) {
      f32x4 v = __builtin_nontemporal_load(&((const f32x4*)X)[i]);
      us4 o;
      #pragma unroll
      for (int j = 0; j < 4; ++j) o[j] = f2b(v[j]);
      ((us4*)Xb)[xidx(i)] = o;
    }
  } else {
    const int s = bx >> 2;
    if (s < WBLK) {
      // ---- W conversion: 16 blocks ----
      const int tid = s * 256 + (int)threadIdx.x;
      for (int i = tid; i < NWV; i += WBLK * 256) {
        f32x4 v = ((const f32x4*)Wm)[i];
        us4 o;
        #pragma unroll
        for (int j = 0; j < 4; ++j) o[j] = f2b(v[j]);
        ((us4*)Wb)[i] = o;
      }
    } else {
      // ---- bucket build: 496 blocks, overlaps with conversion ----
      const int tid = (s - WBLK) * 256 + (int)threadIdx.x;
      for (int i = tid; i < E_N * Q_N; i += BBLK * 256) {
        int v = en[i];
        int pos = atomicAdd(&cnt[v], 1);
        if (pos < SLOT_STRIDE) slots[v * SLOT_STRIDE + pos] = i >> 5;  // edge id
      }
    }
  }
}

// ---- P1: fused edge-mean + GEMM. One 8-edge tile per 512-thread block. -----
// Wave w (0..7) aggregates edge 8t+w alone: 32 fully-independent 1KB wave
// loads (node row [v][b][f] = 1KB covers both batches; us8 = 16B/lane),
// 16 in flight. LDS tile rows 0-7: batch0, rows 8-15: batch1. Stride 264.

__global__ __launch_bounds__(512) void k_agg_gemm(
    const us* __restrict__ Xb, const int* __restrict__ en,
    const us* __restrict__ Wb, us* __restrict__ Yb) {
  __shared__ us tile[16 * LDS_STRIDE];
  const int t = blockIdx.x;
  const int w = threadIdx.x >> 6;      // 0..7: edge within tile
  const int lane = threadIdx.x & 63;
  const int m = lane & 15;
  const int quad = lane >> 4;
  const int half = lane >> 5;          // batch
  const int col8 = (lane & 31) * 8;    // feature col (8 wide)

  const int e = t * 8 + w;
  int nq = en[e * Q_N + (lane & 31)];  // lanes 0-31 hold the 32 node ids
  const us* Xg = Xb + half * F_N + col8;
  float a[8] = {0, 0, 0, 0, 0, 0, 0, 0};
  #pragma unroll 16
  for (int q = 0; q < Q_N; ++q) {      // 16 independent 1KB loads in flight
    int mv = __shfl(nq, q, 64);
    us8 v = *(const us8*)(Xg + (size_t)mv * (2 * F_N));
    #pragma unroll
    for (int j = 0; j < 8; ++j) a[j] += b2f(v[j]);
  }
  const float sc = 1.0f / 32.0f;
  us8 o;
  #pragma unroll
  for (int j = 0; j < 8; ++j) o[j] = f2b(a[j] * sc);
  *(us8*)(tile + (w + 8 * half) * LDS_STRIDE + col8) = o;
  __syncthreads();

  // A-fragments from LDS (reused across this wave's 2 n-tiles)
  bf16x8 af[8];
  #pragma unroll
  for (int kk = 0; kk < 8; ++kk)
    af[kk] = *(const bf16x8*)(tile + m * LDS_STRIDE + quad * 8 + kk * 32);
  #pragma unroll
  for (int i = 0; i < 2; ++i) {
    const int nt = w * 2 + i;
    const us* bp = Wb + (size_t)(nt * 16 + m) * F_N + quad * 8;
    f32x4 acc = {0.f, 0.f, 0.f, 0.f};
    #pragma unroll
    for (int kk = 0; kk < 8; ++kk) {
      bf16x8 bv = *(const bf16x8*)(bp + kk * 32);
      acc = __builtin_amdgcn_mfma_f32_16x16x32_bf16(af[kk], bv, acc, 0, 0, 0);
    }
    #pragma unroll
    for (int r2 = 0; r2 < 4; ++r2) {
      int dr = quad * 4 + r2;            // D row within 16-row tile
      int e2 = t * 8 + (dr & 7);
      int b = dr >> 3;
      Yb[((size_t)e2 * 2 + b) * 256 + nt * 16 + m] = f2b(acc[r2]);  // [e][b][f]
    }
  }
}

// ---- P2: out[b,v,:] = bias + (1/deg) * sum_{e in slots(v)} Y[e,b,:] --------
// Yb [e][b][f]: each per-slot read is ONE coalesced 1KB wave load.

__global__ __launch_bounds__(256) void k_out(
    const us* __restrict__ Yb, const int* __restrict__ cnt,
    const int* __restrict__ slots, const float* __restrict__ bias,
    float* __restrict__ out) {
  const int w = threadIdx.x >> 6;
  const int lane = threadIdx.x & 63;
  const int v = blockIdx.x * 4 + w;
  const int half = lane >> 5;          // batch
  const int col8 = (lane & 31) * 8;
  int c = cnt[v];
  if (c > SLOT_STRIDE) c = SLOT_STRIDE;
  const int* sb = slots + (size_t)v * SLOT_STRIDE;
  const us* Yg = Yb + half * 256 + col8;
  float acc[8] = {0, 0, 0, 0, 0, 0, 0, 0};
  int j = 0;
  for (; j + 4 <= c; j += 4) {
    int ea = sb[j], eb = sb[j + 1], ec = sb[j + 2], ed = sb[j + 3];
    us8 pa = *(const us8*)(Yg + (size_t)ea * 512);
    us8 pb = *(const us8*)(Yg + (size_t)eb * 512);
    us8 pc = *(const us8*)(Yg + (size_t)ec * 512);
    us8 pd = *(const us8*)(Yg + (size_t)ed * 512);
    #pragma unroll
    for (int k = 0; k < 8; ++k)
      acc[k] += (b2f(pa[k]) + b2f(pb[k])) + (b2f(pc[k]) + b2f(pd[k]));
  }
  for (; j < c; ++j) {
    int e = sb[j];
    us8 p = *(const us8*)(Yg + (size_t)e * 512);
    #pragma unroll
    for (int k = 0; k < 8; ++k) acc[k] += b2f(p[k]);
  }
  float inv = 1.0f / (float)(c > 0 ? c : 1);
  f32x4 b0 = *(const f32x4*)(bias + col8);
  f32x4 b1 = *(const f32x4*)(bias + col8 + 4);
  f32x4 r0, r1;
  #pragma unroll
  for (int k = 0; k < 4; ++k) {
    r0[k] = b0[k] + acc[k] * inv;
    r1[k] = b1[k] + acc[4 + k] * inv;
  }
  float* op = out + ((size_t)half * V_N + v) * 256 + col8;
  __builtin_nontemporal_store(r0, (f32x4*)op);       // streaming, never re-read
  __builtin_nontemporal_store(r1, (f32x4*)(op + 4));
}

// ---- launch -----------------------------------------------------------------

extern "C" void kernel_launch(void* const* d_in, const int* in_sizes, int n_in,
                              void* d_out, int out_size, void* d_ws, size_t ws_size,
                              hipStream_t stream) {
  (void)in_sizes; (void)n_in; (void)out_size; (void)ws_size;
  const float* X = (const float*)d_in[0];    // (B,V,F) fp32
  const int* en = (const int*)d_in[1];       // (E,Q) int32
  const float* Wm = (const float*)d_in[2];   // (OUT,F) fp32
  const float* bias = (const float*)d_in[3]; // (OUT,) fp32
  float* out = (float*)d_out;                // (B,V,OUT) fp32

  char* ws = (char*)d_ws;
  int* cnt   = (int*)(ws);                    // V ints = 200,000 B
  int* slots = (int*)(ws + (1u << 20));       // V*40 ints = 8,000,000 B
  us*  Wb    = (us*)(ws + (10u << 20));       // 256*256 bf16 = 131,072 B
  us*  Yb    = (us*)(ws + (11u << 20));       // 2E*256 bf16 = 10,240,000 B
  us*  Xb    = (us*)(ws + (22u << 20));       // B*V*F bf16 = 51,200,000 B

  hipMemsetAsync(cnt, 0, V_N * sizeof(int), stream);
  k_prep_bucket<<<PREP_GRID, 256, 0, stream>>>(X, Wm, en, Xb, Wb, cnt, slots);
  k_agg_gemm<<<T_TILES, 512, 0, stream>>>(Xb, en, Wb, Yb);
  k_out<<<V_N / 4, 256, 0, stream>>>(Yb, cnt, slots, bias, out);
}

// Round 6
// 285.544 us; speedup vs baseline: 1.0940x; 1.0213x over previous
//
#include <hip/hip_runtime.h>
#include <hip/hip_bf16.h>
#include <stdint.h>

// Problem constants (from reference)
static constexpr int V_N = 50000;
static constexpr int E_N = 10000;
static constexpr int Q_N = 32;
static constexpr int F_N = 256;        // F_DIM == OUT_DIM == 256
static constexpr int SLOT_STRIDE = 40; // max degree slots (Poisson mean 6.4)
static constexpr int VF4 = V_N * F_N / 4;        // 3,200,000 vec4 per batch
static constexpr int NXV = 2 * VF4;              // 6,400,000 vec4s of X
static constexpr int NWV = (F_N * F_N) / 4;      // 16,384 vec4s of W
static constexpr int T_TILES = E_N / 8;          // 1250 edge-tiles (8 edges)
static constexpr int LDS_STRIDE = 264;           // 256 + 8 pad

// prep role split: blockIdx%4 in {0,1,2} -> X convert, %4==3 -> W/bucket
static constexpr int PREP_GRID = 2048;
static constexpr int XNT = 1536 * 256;           // X-convert threads (mult of 64)
static constexpr int WBLK = 16;
static constexpr int BBLK = 512 - WBLK;          // 496 bucket blocks

typedef unsigned short us;
typedef float f32x4 __attribute__((ext_vector_type(4)));
typedef us us4 __attribute__((ext_vector_type(4)));
typedef us us8 __attribute__((ext_vector_type(8)));
typedef __bf16 bf16x8 __attribute__((ext_vector_type(8)));

__device__ __forceinline__ us f2b(float f) {
  unsigned x = __builtin_bit_cast(unsigned, f);
  x += 0x7fffu + ((x >> 16) & 1u);   // round-to-nearest-even
  return (us)(x >> 16);
}
__device__ __forceinline__ float b2f(us u) {
  unsigned x = ((unsigned)u) << 16;
  return __builtin_bit_cast(float, x);
}

// vec4 index i over fp32 X[b][v][f]  ->  vec4 index into Xb[v][b][f]
// (wave bases are multiples of 64 and VF4 % 64 == 0, so per-wave stores stay
//  contiguous 512B chunks and no wave straddles the batch boundary)
__device__ __forceinline__ int xidx(int i) {
  int b = (i >= VF4) ? 1 : 0;
  int r2 = i - b * VF4;
  return ((r2 >> 6) << 7) + (b << 6) + (r2 & 63);
}

// ---- P0: fp32->bf16 staging of X,W + bucket-build (role-specialized) -------
// X is read with NON-TEMPORAL loads: it is touched exactly once, and keeping
// it out of L3 leaves the cache for Xb (re-read 6.4x by the gather).

__global__ __launch_bounds__(256) void k_prep_bucket(
    const float* __restrict__ X, const float* __restrict__ Wm,
    const int* __restrict__ en, us* __restrict__ Xb, us* __restrict__ Wb,
    int* __restrict__ cnt, int* __restrict__ slots) {
  const int bx = blockIdx.x;
  const int r = bx & 3;
  if (r != 3) {
    // ---- X conversion: 1536 blocks, 4-way unrolled (64B reads/lane in flight)
    const int tid = ((bx >> 2) * 3 + r) * 256 + (int)threadIdx.x;
    int i = tid;
    for (; i + 3 * XNT < NXV; i += 4 * XNT) {
      f32x4 va = __builtin_nontemporal_load(&((const f32x4*)X)[i]);
      f32x4 vb = __builtin_nontemporal_load(&((const f32x4*)X)[i + XNT]);
      f32x4 vc = __builtin_nontemporal_load(&((const f32x4*)X)[i + 2 * XNT]);
      f32x4 vd = __builtin_nontemporal_load(&((const f32x4*)X)[i + 3 * XNT]);
      us4 oa, ob, oc, od;
      #pragma unroll
      for (int j = 0; j < 4; ++j) {
        oa[j] = f2b(va[j]); ob[j] = f2b(vb[j]);
        oc[j] = f2b(vc[j]); od[j] = f2b(vd[j]);
      }
      ((us4*)Xb)[xidx(i)] = oa;
      ((us4*)Xb)[xidx(i + XNT)] = ob;
      ((us4*)Xb)[xidx(i + 2 * XNT)] = oc;
      ((us4*)Xb)[xidx(i + 3 * XNT)] = od;
    }
    for (; i < NXV; i += XNT) {
      f32x4 v = __builtin_nontemporal_load(&((const f32x4*)X)[i]);
      us4 o;
      #pragma unroll
      for (int j = 0; j < 4; ++j) o[j] = f2b(v[j]);
      ((us4*)Xb)[xidx(i)] = o;
    }
  } else {
    const int s = bx >> 2;
    if (s < WBLK) {
      // ---- W conversion: 16 blocks ----
      const int tid = s * 256 + (int)threadIdx.x;
      for (int i = tid; i < NWV; i += WBLK * 256) {
        f32x4 v = ((const f32x4*)Wm)[i];
        us4 o;
        #pragma unroll
        for (int j = 0; j < 4; ++j) o[j] = f2b(v[j]);
        ((us4*)Wb)[i] = o;
      }
    } else {
      // ---- bucket build: 496 blocks, overlaps with conversion ----
      const int tid = (s - WBLK) * 256 + (int)threadIdx.x;
      for (int i = tid; i < E_N * Q_N; i += BBLK * 256) {
        int v = en[i];
        int pos = atomicAdd(&cnt[v], 1);
        if (pos < SLOT_STRIDE) slots[v * SLOT_STRIDE + pos] = i >> 5;  // edge id
      }
    }
  }
}

// ---- P1: fused edge-mean + GEMM. One 8-edge tile per 512-thread block. -----
// Wave w (0..7) aggregates edge 8t+w. Gather is an explicit 8-deep rolling
// register pipeline (us8 buf[8], static indices only): consume load q while
// q+1..q+7 are in flight and q+8 issues. Node id comes via readlane -> SGPR
// base (SALU address math, no ds_bpermute in the hot loop).
// LDS tile rows 0-7: batch0, rows 8-15: batch1. Stride 264.

__global__ __launch_bounds__(512) void k_agg_gemm(
    const us* __restrict__ Xb, const int* __restrict__ en,
    const us* __restrict__ Wb, us* __restrict__ Yb) {
  __shared__ us tile[16 * LDS_STRIDE];
  const int t = blockIdx.x;
  const int w = threadIdx.x >> 6;      // 0..7: edge within tile
  const int lane = threadIdx.x & 63;
  const int m = lane & 15;
  const int quad = lane >> 4;
  const int half = lane >> 5;          // batch
  const int col8 = (lane & 31) * 8;    // feature col (8 wide)

  const int e = t * 8 + w;
  int nq = en[e * Q_N + (lane & 31)];  // lanes 0-31 hold the 32 node ids
  const us* Xg = Xb + half * F_N + col8;   // per-lane part of the address
  float a[8] = {0, 0, 0, 0, 0, 0, 0, 0};
  us8 buf[8];
  #pragma unroll
  for (int q = 0; q < 8; ++q) {        // prologue: fill the pipeline
    int mv = __builtin_amdgcn_readlane(nq, q);
    buf[q] = *(const us8*)(Xg + (size_t)mv * (2 * F_N));
  }
  #pragma unroll
  for (int q = 0; q < 24; ++q) {       // steady state: 8 loads in flight
    us8 v = buf[q & 7];
    int mv = __builtin_amdgcn_readlane(nq, q + 8);
    buf[q & 7] = *(const us8*)(Xg + (size_t)mv * (2 * F_N));
    #pragma unroll
    for (int j = 0; j < 8; ++j) a[j] += b2f(v[j]);
  }
  #pragma unroll
  for (int q = 24; q < 32; ++q) {      // drain
    us8 v = buf[q & 7];
    #pragma unroll
    for (int j = 0; j < 8; ++j) a[j] += b2f(v[j]);
  }
  const float sc = 1.0f / 32.0f;
  us8 o;
  #pragma unroll
  for (int j = 0; j < 8; ++j) o[j] = f2b(a[j] * sc);
  *(us8*)(tile + (w + 8 * half) * LDS_STRIDE + col8) = o;
  __syncthreads();

  // A-fragments from LDS (reused across this wave's 2 n-tiles)
  bf16x8 af[8];
  #pragma unroll
  for (int kk = 0; kk < 8; ++kk)
    af[kk] = *(const bf16x8*)(tile + m * LDS_STRIDE + quad * 8 + kk * 32);
  #pragma unroll
  for (int i = 0; i < 2; ++i) {
    const int nt = w * 2 + i;
    const us* bp = Wb + (size_t)(nt * 16 + m) * F_N + quad * 8;
    f32x4 acc = {0.f, 0.f, 0.f, 0.f};
    #pragma unroll
    for (int kk = 0; kk < 8; ++kk) {
      bf16x8 bv = *(const bf16x8*)(bp + kk * 32);
      acc = __builtin_amdgcn_mfma_f32_16x16x32_bf16(af[kk], bv, acc, 0, 0, 0);
    }
    #pragma unroll
    for (int r2 = 0; r2 < 4; ++r2) {
      int dr = quad * 4 + r2;            // D row within 16-row tile
      int e2 = t * 8 + (dr & 7);
      int b = dr >> 3;
      Yb[((size_t)e2 * 2 + b) * 256 + nt * 16 + m] = f2b(acc[r2]);  // [e][b][f]
    }
  }
}

// ---- P2: out[b,v,:] = bias + (1/deg) * sum_{e in slots(v)} Y[e,b,:] --------
// Yb [e][b][f]: each per-slot read is ONE coalesced 1KB wave load.

__global__ __launch_bounds__(256) void k_out(
    const us* __restrict__ Yb, const int* __restrict__ cnt,
    const int* __restrict__ slots, const float* __restrict__ bias,
    float* __restrict__ out) {
  const int w = threadIdx.x >> 6;
  const int lane = threadIdx.x & 63;
  const int v = blockIdx.x * 4 + w;
  const int half = lane >> 5;          // batch
  const int col8 = (lane & 31) * 8;
  int c = cnt[v];
  if (c > SLOT_STRIDE) c = SLOT_STRIDE;
  const int* sb = slots + (size_t)v * SLOT_STRIDE;
  const us* Yg = Yb + half * 256 + col8;
  float acc[8] = {0, 0, 0, 0, 0, 0, 0, 0};
  int j = 0;
  for (; j + 4 <= c; j += 4) {
    int ea = sb[j], eb = sb[j + 1], ec = sb[j + 2], ed = sb[j + 3];
    us8 pa = *(const us8*)(Yg + (size_t)ea * 512);
    us8 pb = *(const us8*)(Yg + (size_t)eb * 512);
    us8 pc = *(const us8*)(Yg + (size_t)ec * 512);
    us8 pd = *(const us8*)(Yg + (size_t)ed * 512);
    #pragma unroll
    for (int k = 0; k < 8; ++k)
      acc[k] += (b2f(pa[k]) + b2f(pb[k])) + (b2f(pc[k]) + b2f(pd[k]));
  }
  for (; j < c; ++j) {
    int e = sb[j];
    us8 p = *(const us8*)(Yg + (size_t)e * 512);
    #pragma unroll
    for (int k = 0; k < 8; ++k) acc[k] += b2f(p[k]);
  }
  float inv = 1.0f / (float)(c > 0 ? c : 1);
  f32x4 b0 = *(const f32x4*)(bias + col8);
  f32x4 b1 = *(const f32x4*)(bias + col8 + 4);
  f32x4 r0, r1;
  #pragma unroll
  for (int k = 0; k < 4; ++k) {
    r0[k] = b0[k] + acc[k] * inv;
    r1[k] = b1[k] + acc[4 + k] * inv;
  }
  float* op = out + ((size_t)half * V_N + v) * 256 + col8;
  __builtin_nontemporal_store(r0, (f32x4*)op);       // streaming, never re-read
  __builtin_nontemporal_store(r1, (f32x4*)(op + 4));
}

// ---- launch -----------------------------------------------------------------

extern "C" void kernel_launch(void* const* d_in, const int* in_sizes, int n_in,
                              void* d_out, int out_size, void* d_ws, size_t ws_size,
                              hipStream_t stream) {
  (void)in_sizes; (void)n_in; (void)out_size; (void)ws_size;
  const float* X = (const float*)d_in[0];    // (B,V,F) fp32
  const int* en = (const int*)d_in[1];       // (E,Q) int32
  const float* Wm = (const float*)d_in[2];   // (OUT,F) fp32
  const float* bias = (const float*)d_in[3]; // (OUT,) fp32
  float* out = (float*)d_out;                // (B,V,OUT) fp32

  char* ws = (char*)d_ws;
  int* cnt   = (int*)(ws);                    // V ints = 200,000 B
  int* slots = (int*)(ws + (1u << 20));       // V*40 ints = 8,000,000 B
  us*  Wb    = (us*)(ws + (10u << 20));       // 256*256 bf16 = 131,072 B
  us*  Yb    = (us*)(ws + (11u << 20));       // 2E*256 bf16 = 10,240,000 B
  us*  Xb    = (us*)(ws + (22u << 20));       // B*V*F bf16 = 51,200,000 B

  hipMemsetAsync(cnt, 0, V_N * sizeof(int), stream);
  k_prep_bucket<<<PREP_GRID, 256, 0, stream>>>(X, Wm, en, Xb, Wb, cnt, slots);
  k_agg_gemm<<<T_TILES, 512, 0, stream>>>(Xb, en, Wb, Yb);
  k_out<<<V_N / 4, 256, 0, stream>>>(Yb, cnt, slots, bias, out);
}